// Round 5
// baseline (69.762 us; speedup 1.0000x reference)
//
#include <hip/hip_runtime.h>

// BERT_CRF, 16th-partitioned, VALU emissions, W in LDS. B=64,T=512,H=768,L=9.
//
// Round-4 lesson (VGPR_Count=80 < the 108 wreg floats requested): the
// compiler refused W-in-registers and re-materialized W from memory every
// row -> ~30 VMEM instr/row/lane -> TA request-rate bound at 0.8 TB/s.
// Here W is staged ONCE per block into LDS (27 KB) and read via
// ds_read_b128 (consecutive-float4 layout, 1KB/wave/instr, minimum-phase),
// register-blocked 2 rows per W read. No per-lane W copies, no spill.
//
// K1 emis_kernel: grid 1024 = (b, p of 16 x 32 rows), 256 thr (4 waves),
//   __launch_bounds__(256,4) -> 16 waves/CU (4 blocks/CU).
//   Phase A: stage W->LDS, eTs, mask slice. barrier.
//   Phase B: wave w computes rows [w*8, +8) as 4 pairs: 6 contiguous
//     float4 loads (1KB/wave each), 27 ds_read_b128 of W, 216 FMA,
//     dual 6-level __shfl_xor butterfly, lanes<9 write exp -> ldsE. barrier.
//   Phase C (parallel by wave): w0/w1 = 16-step chunk products (proven
//     code) for chunks 2p/2p+1; w2 = numerator partials; w3 = em0. barrier.
//   Phase D: wave0 pair-combines the 2 chunks (= round-3's s2 level,
//     identical association) -> Mq[bid], lgq[bid].
// K2 comb_kernel: 64 blocks x 128 thr. 16->8->4 pair-combines + proven
//   serial fold of 4 + election reduce -> out. Tree bit-identical to the
//   proven round-3 tree. cnt zeroed by K1 block 0.

#define Bn 64
#define Tn 512
#define Hn 768
#define Ln 9
#define EMS 12     // padded LDS emission row stride (floats)
#define PT 32      // timesteps per block (2 chunks of 16)
#define NBLK 1024  // Bn * 16

// Proven pair-combine: (A,lgA) then (B,lgB) -> out (row-scaled) + outLg.
__device__ __forceinline__ void pair_combine(
    const float (*MA)[Ln], const float* lgA,
    const float (*MB)[Ln], const float* lgB,
    int r, float* outM, float* outLg)
{
    float mB = lgB[0];
#pragma unroll
    for (int k = 1; k < 9; ++k) mB = fmaxf(mB, lgB[k]);
    float tA[9];
#pragma unroll
    for (int k = 0; k < 9; ++k) tA[k] = MA[r][k] * __expf(lgB[k] - mB);
    float v[9];
#pragma unroll
    for (int jj = 0; jj < 9; ++jj) {
        float acc = tA[0] * MB[0][jj];
#pragma unroll
        for (int k = 1; k < 9; ++k) acc += tA[k] * MB[k][jj];
        v[jj] = acc;
    }
    float mx = v[0];
#pragma unroll
    for (int jj = 1; jj < 9; ++jj) mx = fmaxf(mx, v[jj]);
    float inv = 1.f / mx;
#pragma unroll
    for (int jj = 0; jj < 9; ++jj) outM[jj] = v[jj] * inv;
    *outLg = lgA[r] + mB + __logf(mx);
}

// ---------------- K1 ----------------
__global__ __launch_bounds__(256, 4) void emis_kernel(
    const float* __restrict__ wv, const float* __restrict__ Wm,
    const float* __restrict__ bias, const int* __restrict__ mask,
    const int* __restrict__ label, const float* __restrict__ trans,
    const float* __restrict__ startT,
    float* __restrict__ Mq, float* __restrict__ lgq,
    float* __restrict__ numq, int* __restrict__ msq,
    float* __restrict__ em0, int* __restrict__ cnt)
{
    __shared__ __align__(16) float4 wf4[9 * 3 * 64];   // 27648 B: W[l][seg][lane]
    __shared__ __align__(16) float  ldsE[PT][EMS];     // exp(emissions)
    __shared__ int   ldsM[PT];                         // mask slice
    __shared__ float eTs[81];                          // exp(transitions)
    __shared__ float sM[2][Ln][Ln];                    // 2 chunk matrices
    __shared__ float sLg[2][Ln];

    const int tid   = threadIdx.x;
    const int lane  = tid & 63;
    const int wid   = tid >> 6;
    const int bid   = blockIdx.x;
    const int b     = bid >> 4;
    const int p     = bid & 15;
    const int tbase = p * PT;

    if (bid == 0 && tid == 0) cnt[0] = 0;   // K2 runs strictly after K1

    // ---- Phase A: stage W (float4 lane layout), eTs, mask ----
    for (int f = tid; f < 1728; f += 256) {
        const int l = f / 192, rem = f % 192;          // rem = seg*64 + ln2
        wf4[f] = *reinterpret_cast<const float4*>(
            Wm + l * Hn + (rem >> 6) * 256 + ((rem & 63) << 2));
    }
    if (tid < 81) eTs[tid] = __expf(trans[tid]);
    if (tid < PT) ldsM[tid] = mask[b * Tn + tbase + tid];
    __syncthreads();

    // ---- Phase B: emissions, wave wid -> rows [wid*8, +8), 4 pairs ----
    {
        const float biasv = (lane < Ln) ? bias[lane] : 0.f;
        const float* rowp = wv + (size_t)(bid * PT + wid * 8) * Hn + (lane << 2);

#pragma unroll 2
        for (int pr = 0; pr < 4; ++pr) {
            const float* s0 = rowp + (2 * pr) * Hn;
            const float* s1 = s0 + Hn;
            float4 a0 = *reinterpret_cast<const float4*>(s0);
            float4 a1 = *reinterpret_cast<const float4*>(s0 + 256);
            float4 a2 = *reinterpret_cast<const float4*>(s0 + 512);
            float4 b0 = *reinterpret_cast<const float4*>(s1);
            float4 b1 = *reinterpret_cast<const float4*>(s1 + 256);
            float4 b2 = *reinterpret_cast<const float4*>(s1 + 512);

            float acc0[9], acc1[9];
#pragma unroll
            for (int l = 0; l < 9; ++l) {
                float4 w0 = wf4[l * 192 + lane];
                float4 w1 = wf4[l * 192 + 64 + lane];
                float4 w2 = wf4[l * 192 + 128 + lane];
                float u = a0.x * w0.x;  float t = b0.x * w0.x;
                u += a0.y * w0.y;  t += b0.y * w0.y;
                u += a0.z * w0.z;  t += b0.z * w0.z;
                u += a0.w * w0.w;  t += b0.w * w0.w;
                u += a1.x * w1.x;  t += b1.x * w1.x;
                u += a1.y * w1.y;  t += b1.y * w1.y;
                u += a1.z * w1.z;  t += b1.z * w1.z;
                u += a1.w * w1.w;  t += b1.w * w1.w;
                u += a2.x * w2.x;  t += b2.x * w2.x;
                u += a2.y * w2.y;  t += b2.y * w2.y;
                u += a2.z * w2.z;  t += b2.z * w2.z;
                u += a2.w * w2.w;  t += b2.w * w2.w;
                acc0[l] = u; acc1[l] = t;
            }
            // dual 64-lane butterfly (18 independent chains per level)
#pragma unroll
            for (int off = 32; off > 0; off >>= 1) {
#pragma unroll
                for (int l = 0; l < 9; ++l) {
                    acc0[l] += __shfl_xor(acc0[l], off);
                    acc1[l] += __shfl_xor(acc1[l], off);
                }
            }
            float v0 = acc0[0], v1 = acc1[0];
#pragma unroll
            for (int l = 1; l < 9; ++l) {
                v0 = (lane == l) ? acc0[l] : v0;
                v1 = (lane == l) ? acc1[l] : v1;
            }
            if (lane < Ln) {
                ldsE[wid * 8 + 2 * pr][lane]     = __expf(v0 + biasv);
                ldsE[wid * 8 + 2 * pr + 1][lane] = __expf(v1 + biasv);
            }
        }
    }
    __syncthreads();

    // ---- Phase C: parallel tails by wave ----
    if (wid < 2) {
        // chunk product for chunk wid (rows [wid*16, +16)), lanes 0..8
        if (lane < Ln) {
            float Tr[81];
#pragma unroll
            for (int i = 0; i < 81; ++i) Tr[i] = eTs[i];
            const int r = lane;
            float v[9];
#pragma unroll
            for (int k = 0; k < 9; ++k) v[k] = (k == r) ? 1.f : 0.f;
            float lg = 0.f;
            const int sstart = (tbase + wid * 16 == 0) ? 1 : 0;   // skip t=0
            for (int s = sstart; s < 16; ++s) {
                const int lrow = wid * 16 + s;
                if (ldsM[lrow]) {
                    float4 e0v = *reinterpret_cast<const float4*>(&ldsE[lrow][0]);
                    float4 e1v = *reinterpret_cast<const float4*>(&ldsE[lrow][4]);
                    float  e8  = ldsE[lrow][8];
                    float e[9] = {e0v.x, e0v.y, e0v.z, e0v.w,
                                  e1v.x, e1v.y, e1v.z, e1v.w, e8};
                    float nv[9];
#pragma unroll
                    for (int jj = 0; jj < 9; ++jj) {
                        float a2 = v[0] * Tr[jj];
#pragma unroll
                        for (int k = 1; k < 9; ++k) a2 += v[k] * Tr[k * 9 + jj];
                        nv[jj] = a2 * e[jj];
                    }
                    float mx = nv[0];
#pragma unroll
                    for (int jj = 1; jj < 9; ++jj) mx = fmaxf(mx, nv[jj]);
                    float inv = 1.f / mx;
#pragma unroll
                    for (int jj = 0; jj < 9; ++jj) v[jj] = nv[jj] * inv;
                    lg += __logf(mx);
                }
            }
#pragma unroll
            for (int jj = 0; jj < 9; ++jj) sM[wid][r][jj] = v[jj];
            sLg[wid][r] = lg;
        }
    } else if (wid == 2) {
        // numerator partials for this block's 32 timesteps
        float part = 0.f; int ms = 0;
        if (lane < PT) {
            const int gt  = tbase + lane;
            const int tag = label[b * Tn + gt];
            const int mk  = ldsM[lane];
            ms = mk;
            if (gt == 0) {
                part = startT[tag] + __logf(ldsE[0][tag]);
            } else if (mk) {
                const int prev = label[b * Tn + gt - 1];
                part = trans[prev * Ln + tag] + __logf(ldsE[lane][tag]);
            }
        }
#pragma unroll
        for (int off = 32; off > 0; off >>= 1) {
            part += __shfl_xor(part, off);
            ms   += __shfl_xor(ms, off);
        }
        if (lane == 0) { numq[bid] = part; msq[bid] = ms; }
    } else {
        if (p == 0 && lane < Ln) em0[b * Ln + lane] = ldsE[0][lane];
    }
    __syncthreads();

    // ---- Phase D: wave0 combines the 2 chunks -> global (round-3 s2 level) ----
    if (wid == 0 && lane < Ln) {
        const int r = lane;
        float om[9], ol;
        pair_combine(sM[0], sLg[0], sM[1], sLg[1], r, om, &ol);
#pragma unroll
        for (int jj = 0; jj < 9; ++jj) Mq[bid * 81 + r * 9 + jj] = om[jj];
        lgq[bid * Ln + r] = ol;
    }
}

// ---------------- K2: combine 16 matrices per batch ----------------
__global__ __launch_bounds__(128) void comb_kernel(
    const float* __restrict__ Mq, const float* __restrict__ lgq,
    const float* __restrict__ numq, const int* __restrict__ msq,
    const float* __restrict__ em0, const int* __restrict__ label,
    const float* __restrict__ startT, const float* __restrict__ endT,
    float* __restrict__ partial, int* __restrict__ cnt, float* __restrict__ out)
{
    __shared__ float cO[16][Ln][Ln];
    __shared__ float cOl[16][Ln];
    __shared__ float cP[8][Ln][Ln];
    __shared__ float cPl[8][Ln];
    __shared__ float cQ[4][Ln][Ln];
    __shared__ float cQl[4][Ln];
    __shared__ float cem[Ln];
    __shared__ float cnum[16];
    __shared__ int   cms[16];

    const int b = blockIdx.x, tid = threadIdx.x;

    for (int i = tid; i < 16 * 81; i += 128) ((float*)cO)[i]  = Mq[b * 1296 + i];
    for (int i = tid; i < 16 * 9;  i += 128) ((float*)cOl)[i] = lgq[b * 144 + i];
    if (tid < Ln) cem[tid] = em0[b * Ln + tid];
    if (tid < 16) { cnum[tid] = numq[b * 16 + tid]; cms[tid] = msq[b * 16 + tid]; }
    __syncthreads();

    // 16 -> 8 (round-3's in-block oct level)
    if (tid < 8 * Ln) {
        const int pp = tid / Ln, r = tid % Ln;
        float om[9], ol;
        pair_combine(cO[2 * pp], cOl[2 * pp], cO[2 * pp + 1], cOl[2 * pp + 1],
                     r, om, &ol);
#pragma unroll
        for (int jj = 0; jj < 9; ++jj) cP[pp][r][jj] = om[jj];
        cPl[pp][r] = ol;
    }
    __syncthreads();

    // 8 -> 4 (octs -> quarters)
    if (tid < 4 * Ln) {
        const int pp = tid / Ln, r = tid % Ln;
        float om[9], ol;
        pair_combine(cP[2 * pp], cPl[2 * pp], cP[2 * pp + 1], cPl[2 * pp + 1],
                     r, om, &ol);
#pragma unroll
        for (int jj = 0; jj < 9; ++jj) cQ[pp][r][jj] = om[jj];
        cQl[pp][r] = ol;
    }
    __syncthreads();

    // serial fold of 4 quarters + denominator (proven)
    if (tid < 16) {
        const int lj = tid;
        const float NEG = -1e30f;
        float la = (lj < Ln) ? (startT[lj] + __logf(cem[lj])) : NEG;
        for (int c = 0; c < 4; ++c) {
            float mc[9];
#pragma unroll
            for (int rr = 0; rr < 9; ++rr) mc[rr] = (lj < Ln) ? cQ[c][rr][lj] : 0.f;
            float x = (lj < Ln) ? (la + cQl[c][lj]) : NEG;
            float mm = x;
#pragma unroll
            for (int off = 1; off < 16; off <<= 1) mm = fmaxf(mm, __shfl_xor(mm, off, 16));
            float w = __expf(x - mm);                 // lj>=9 -> 0
            float sacc = 0.f;
#pragma unroll
            for (int rr = 0; rr < 9; ++rr) sacc += __shfl(w, rr, 16) * mc[rr];
            la = (lj < Ln) ? (mm + __logf(sacc)) : NEG;
        }
        float x = (lj < Ln) ? (la + endT[lj]) : NEG;
        float mm = x;
#pragma unroll
        for (int off = 1; off < 16; off <<= 1) mm = fmaxf(mm, __shfl_xor(mm, off, 16));
        float se = __expf(x - mm);
#pragma unroll
        for (int off = 1; off < 16; off <<= 1) se += __shfl_xor(se, off, 16);
        if (lj == 0) {
            float denom = mm + __logf(se);
            float numer = 0.f; int sm = 0;
#pragma unroll
            for (int i = 0; i < 16; ++i) { numer += cnum[i]; sm += cms[i]; }
            int last = label[b * Tn + sm - 1];
            partial[b] = denom - (numer + endT[last]);   // = -llh[b]
        }
    }

    // last block reduces partials -> out (proven election, wave 0 only)
    if (tid < 64) {
        int old = 0;
        if (tid == 0) {
            __threadfence();
            old = atomicAdd(cnt, 1);
        }
        old = __shfl(old, 0);
        if (old == Bn - 1) {
            __threadfence();             // acquire: other blocks' partial[] visible
            float pv = partial[tid];
#pragma unroll
            for (int off = 32; off > 0; off >>= 1) pv += __shfl_xor(pv, off);
            if (tid == 0) out[0] = pv * (1.0f / Bn);
        }
    }
}

extern "C" void kernel_launch(void* const* d_in, const int* in_sizes, int n_in,
                              void* d_out, int out_size, void* d_ws, size_t ws_size,
                              hipStream_t stream)
{
    // inputs: 0=length(unused) 1=word2vec 2=mask 3=label 4=W 5=b 6=start 7=end 8=trans
    const float* wv    = (const float*)d_in[1];
    const int*   mask  = (const int*)d_in[2];
    const int*   label = (const int*)d_in[3];
    const float* Wm    = (const float*)d_in[4];
    const float* bias  = (const float*)d_in[5];
    const float* st    = (const float*)d_in[6];
    const float* en    = (const float*)d_in[7];
    const float* tr    = (const float*)d_in[8];

    float* ws      = (float*)d_ws;
    float* Mq      = ws;                    // 1024*81 = 82944
    float* lgq     = ws + 82944;            // 1024*9  = 9216
    float* numq    = ws + 92160;            // 1024
    int*   msq     = (int*)(ws + 93184);    // 1024
    float* em0     = ws + 94208;            // 64*9 = 576
    float* partial = ws + 94784;            // 64
    int*   cnt     = (int*)(ws + 94848);    // 1
    float* out     = (float*)d_out;

    hipLaunchKernelGGL(emis_kernel, dim3(NBLK), dim3(256), 0, stream,
                       wv, Wm, bias, mask, label, tr, st,
                       Mq, lgq, numq, msq, em0, cnt);
    hipLaunchKernelGGL(comb_kernel, dim3(Bn), dim3(128), 0, stream,
                       Mq, lgq, numq, msq, em0, label, st, en,
                       partial, cnt, out);
}

// Round 6
// 61.412 us; speedup vs baseline: 1.1360x; 1.1360x over previous
//
#include <hip/hip_runtime.h>

// BERT_CRF, 16th-partitioned, VALU emissions, W in LDS, spill-free.
// B=64, T=512, H=768, L=9.
//
// Round-5 post-mortem: WRITE_SIZE 34 MB = scratch spill (VGPR capped at 64
// by the ',4' launch-bounds hint vs ~70 live in dual-row phase B + Tr[81]
// in phase C). Steady dispatches still hit 1.8 TB/s @ 41% occupancy -> the
// 1KB-contiguous-per-instruction load engine is right; the register budget
// was blown. This round removes pressure only:
//   - single-row phase B (~45 live regs), no dual-row blocking
//   - plain __launch_bounds__(256) (round-4-proven sane allocation)
//   - phase C reads eTs from LDS at use (no Tr[81] array; round-2 proven)
//
// K1 emis_kernel: grid 1024 = (b, p of 16 x 32 rows), 256 thr (4 waves).
//   Phase A: stage W->LDS as wf4[l][seg][lane] (27.6 KB), eTs, mask. barrier.
//   Phase B: wave w rows [w*8,+8): per row 3 contiguous float4 loads
//     (1KB/wave/instr), 27 ds_read_b128 of W, 108 FMA, 6-level butterfly,
//     lanes<9 write exp -> ldsE. barrier.
//   Phase C: w0/w1 = 16-step chunk products (proven math, eTs from LDS);
//     w2 = numerator partials; w3 = em0. barrier.
//   Phase D: wave0 pair-combines the 2 chunks -> Mq[bid], lgq[bid].
// K2 comb_kernel: verbatim round-5 (passed): 16->8->4 pair-combines +
//   serial fold of 4 + election reduce -> out. cnt zeroed by K1 block 0.

#define Bn 64
#define Tn 512
#define Hn 768
#define Ln 9
#define EMS 12     // padded LDS emission row stride (floats)
#define PT 32      // timesteps per block (2 chunks of 16)
#define NBLK 1024  // Bn * 16

// Proven pair-combine: (A,lgA) then (B,lgB) -> out (row-scaled) + outLg.
__device__ __forceinline__ void pair_combine(
    const float (*MA)[Ln], const float* lgA,
    const float (*MB)[Ln], const float* lgB,
    int r, float* outM, float* outLg)
{
    float mB = lgB[0];
#pragma unroll
    for (int k = 1; k < 9; ++k) mB = fmaxf(mB, lgB[k]);
    float tA[9];
#pragma unroll
    for (int k = 0; k < 9; ++k) tA[k] = MA[r][k] * __expf(lgB[k] - mB);
    float v[9];
#pragma unroll
    for (int jj = 0; jj < 9; ++jj) {
        float acc = tA[0] * MB[0][jj];
#pragma unroll
        for (int k = 1; k < 9; ++k) acc += tA[k] * MB[k][jj];
        v[jj] = acc;
    }
    float mx = v[0];
#pragma unroll
    for (int jj = 1; jj < 9; ++jj) mx = fmaxf(mx, v[jj]);
    float inv = 1.f / mx;
#pragma unroll
    for (int jj = 0; jj < 9; ++jj) outM[jj] = v[jj] * inv;
    *outLg = lgA[r] + mB + __logf(mx);
}

// ---------------- K1 ----------------
__global__ __launch_bounds__(256) void emis_kernel(
    const float* __restrict__ wv, const float* __restrict__ Wm,
    const float* __restrict__ bias, const int* __restrict__ mask,
    const int* __restrict__ label, const float* __restrict__ trans,
    const float* __restrict__ startT,
    float* __restrict__ Mq, float* __restrict__ lgq,
    float* __restrict__ numq, int* __restrict__ msq,
    float* __restrict__ em0, int* __restrict__ cnt)
{
    __shared__ __align__(16) float4 wf4[9 * 3 * 64];   // 27648 B: W[l][seg][lane]
    __shared__ __align__(16) float  ldsE[PT][EMS];     // exp(emissions)
    __shared__ int   ldsM[PT];                         // mask slice
    __shared__ float eTs[81];                          // exp(transitions)
    __shared__ float sM[2][Ln][Ln];                    // 2 chunk matrices
    __shared__ float sLg[2][Ln];

    const int tid   = threadIdx.x;
    const int lane  = tid & 63;
    const int wid   = tid >> 6;
    const int bid   = blockIdx.x;
    const int b     = bid >> 4;
    const int p     = bid & 15;
    const int tbase = p * PT;

    if (bid == 0 && tid == 0) cnt[0] = 0;   // K2 runs strictly after K1

    // ---- Phase A: stage W (float4 lane layout), eTs, mask ----
    for (int f = tid; f < 1728; f += 256) {
        const int l = f / 192, rem = f % 192;          // rem = seg*64 + ln2
        wf4[f] = *reinterpret_cast<const float4*>(
            Wm + l * Hn + (rem >> 6) * 256 + ((rem & 63) << 2));
    }
    if (tid < 81) eTs[tid] = __expf(trans[tid]);
    if (tid < PT) ldsM[tid] = mask[b * Tn + tbase + tid];
    __syncthreads();

    // ---- Phase B: emissions, wave wid -> rows [wid*8, +8), one at a time ----
    {
        const float biasv = (lane < Ln) ? bias[lane] : 0.f;
        const float* rowp = wv + (size_t)(bid * PT + wid * 8) * Hn + (lane << 2);

#pragma unroll 1
        for (int row = 0; row < 8; ++row) {
            const float* src = rowp + row * Hn;
            float4 a0 = *reinterpret_cast<const float4*>(src);        // 1KB/wave
            float4 a1 = *reinterpret_cast<const float4*>(src + 256);  // contiguous
            float4 a2 = *reinterpret_cast<const float4*>(src + 512);

            float acc[9];
#pragma unroll
            for (int l = 0; l < 9; ++l) {
                float4 w0 = wf4[l * 192 + lane];
                float4 w1 = wf4[l * 192 + 64 + lane];
                float4 w2 = wf4[l * 192 + 128 + lane];
                float u = a0.x * w0.x;
                u += a0.y * w0.y; u += a0.z * w0.z; u += a0.w * w0.w;
                u += a1.x * w1.x; u += a1.y * w1.y;
                u += a1.z * w1.z; u += a1.w * w1.w;
                u += a2.x * w2.x; u += a2.y * w2.y;
                u += a2.z * w2.z; u += a2.w * w2.w;
                acc[l] = u;
            }
            // 64-lane butterfly: every lane ends with all 9 totals
#pragma unroll
            for (int off = 32; off > 0; off >>= 1) {
#pragma unroll
                for (int l = 0; l < 9; ++l) acc[l] += __shfl_xor(acc[l], off);
            }
            float v0 = acc[0];
#pragma unroll
            for (int l = 1; l < 9; ++l) v0 = (lane == l) ? acc[l] : v0;
            if (lane < Ln) ldsE[wid * 8 + row][lane] = __expf(v0 + biasv);
        }
    }
    __syncthreads();

    // ---- Phase C: parallel tails by wave ----
    if (wid < 2) {
        // chunk product for chunk wid (rows [wid*16, +16)), lanes 0..8.
        // eTs read from LDS at use -> no 81-register array (round-2 proven).
        if (lane < Ln) {
            const int r = lane;
            float v[9];
#pragma unroll
            for (int k = 0; k < 9; ++k) v[k] = (k == r) ? 1.f : 0.f;
            float lg = 0.f;
            const int sstart = (tbase + wid * 16 == 0) ? 1 : 0;   // skip t=0
            for (int s = sstart; s < 16; ++s) {
                const int lrow = wid * 16 + s;
                if (ldsM[lrow]) {
                    float4 e0v = *reinterpret_cast<const float4*>(&ldsE[lrow][0]);
                    float4 e1v = *reinterpret_cast<const float4*>(&ldsE[lrow][4]);
                    float  e8  = ldsE[lrow][8];
                    float e[9] = {e0v.x, e0v.y, e0v.z, e0v.w,
                                  e1v.x, e1v.y, e1v.z, e1v.w, e8};
                    float nv[9];
#pragma unroll
                    for (int jj = 0; jj < 9; ++jj) {
                        float a2 = v[0] * eTs[jj];
#pragma unroll
                        for (int k = 1; k < 9; ++k) a2 += v[k] * eTs[k * 9 + jj];
                        nv[jj] = a2 * e[jj];
                    }
                    float mx = nv[0];
#pragma unroll
                    for (int jj = 1; jj < 9; ++jj) mx = fmaxf(mx, nv[jj]);
                    float inv = 1.f / mx;
#pragma unroll
                    for (int jj = 0; jj < 9; ++jj) v[jj] = nv[jj] * inv;
                    lg += __logf(mx);
                }
            }
#pragma unroll
            for (int jj = 0; jj < 9; ++jj) sM[wid][r][jj] = v[jj];
            sLg[wid][r] = lg;
        }
    } else if (wid == 2) {
        // numerator partials for this block's 32 timesteps
        float part = 0.f; int ms = 0;
        if (lane < PT) {
            const int gt  = tbase + lane;
            const int tag = label[b * Tn + gt];
            const int mk  = ldsM[lane];
            ms = mk;
            if (gt == 0) {
                part = startT[tag] + __logf(ldsE[0][tag]);
            } else if (mk) {
                const int prev = label[b * Tn + gt - 1];
                part = trans[prev * Ln + tag] + __logf(ldsE[lane][tag]);
            }
        }
#pragma unroll
        for (int off = 32; off > 0; off >>= 1) {
            part += __shfl_xor(part, off);
            ms   += __shfl_xor(ms, off);
        }
        if (lane == 0) { numq[bid] = part; msq[bid] = ms; }
    } else {
        if (p == 0 && lane < Ln) em0[b * Ln + lane] = ldsE[0][lane];
    }
    __syncthreads();

    // ---- Phase D: wave0 combines the 2 chunks -> global ----
    if (wid == 0 && lane < Ln) {
        const int r = lane;
        float om[9], ol;
        pair_combine(sM[0], sLg[0], sM[1], sLg[1], r, om, &ol);
#pragma unroll
        for (int jj = 0; jj < 9; ++jj) Mq[bid * 81 + r * 9 + jj] = om[jj];
        lgq[bid * Ln + r] = ol;
    }
}

// ---------------- K2: combine 16 matrices per batch (round-5 verbatim) ----------------
__global__ __launch_bounds__(128) void comb_kernel(
    const float* __restrict__ Mq, const float* __restrict__ lgq,
    const float* __restrict__ numq, const int* __restrict__ msq,
    const float* __restrict__ em0, const int* __restrict__ label,
    const float* __restrict__ startT, const float* __restrict__ endT,
    float* __restrict__ partial, int* __restrict__ cnt, float* __restrict__ out)
{
    __shared__ float cO[16][Ln][Ln];
    __shared__ float cOl[16][Ln];
    __shared__ float cP[8][Ln][Ln];
    __shared__ float cPl[8][Ln];
    __shared__ float cQ[4][Ln][Ln];
    __shared__ float cQl[4][Ln];
    __shared__ float cem[Ln];
    __shared__ float cnum[16];
    __shared__ int   cms[16];

    const int b = blockIdx.x, tid = threadIdx.x;

    for (int i = tid; i < 16 * 81; i += 128) ((float*)cO)[i]  = Mq[b * 1296 + i];
    for (int i = tid; i < 16 * 9;  i += 128) ((float*)cOl)[i] = lgq[b * 144 + i];
    if (tid < Ln) cem[tid] = em0[b * Ln + tid];
    if (tid < 16) { cnum[tid] = numq[b * 16 + tid]; cms[tid] = msq[b * 16 + tid]; }
    __syncthreads();

    // 16 -> 8
    if (tid < 8 * Ln) {
        const int pp = tid / Ln, r = tid % Ln;
        float om[9], ol;
        pair_combine(cO[2 * pp], cOl[2 * pp], cO[2 * pp + 1], cOl[2 * pp + 1],
                     r, om, &ol);
#pragma unroll
        for (int jj = 0; jj < 9; ++jj) cP[pp][r][jj] = om[jj];
        cPl[pp][r] = ol;
    }
    __syncthreads();

    // 8 -> 4
    if (tid < 4 * Ln) {
        const int pp = tid / Ln, r = tid % Ln;
        float om[9], ol;
        pair_combine(cP[2 * pp], cPl[2 * pp], cP[2 * pp + 1], cPl[2 * pp + 1],
                     r, om, &ol);
#pragma unroll
        for (int jj = 0; jj < 9; ++jj) cQ[pp][r][jj] = om[jj];
        cQl[pp][r] = ol;
    }
    __syncthreads();

    // serial fold of 4 quarters + denominator (proven)
    if (tid < 16) {
        const int lj = tid;
        const float NEG = -1e30f;
        float la = (lj < Ln) ? (startT[lj] + __logf(cem[lj])) : NEG;
        for (int c = 0; c < 4; ++c) {
            float mc[9];
#pragma unroll
            for (int rr = 0; rr < 9; ++rr) mc[rr] = (lj < Ln) ? cQ[c][rr][lj] : 0.f;
            float x = (lj < Ln) ? (la + cQl[c][lj]) : NEG;
            float mm = x;
#pragma unroll
            for (int off = 1; off < 16; off <<= 1) mm = fmaxf(mm, __shfl_xor(mm, off, 16));
            float w = __expf(x - mm);                 // lj>=9 -> 0
            float sacc = 0.f;
#pragma unroll
            for (int rr = 0; rr < 9; ++rr) sacc += __shfl(w, rr, 16) * mc[rr];
            la = (lj < Ln) ? (mm + __logf(sacc)) : NEG;
        }
        float x = (lj < Ln) ? (la + endT[lj]) : NEG;
        float mm = x;
#pragma unroll
        for (int off = 1; off < 16; off <<= 1) mm = fmaxf(mm, __shfl_xor(mm, off, 16));
        float se = __expf(x - mm);
#pragma unroll
        for (int off = 1; off < 16; off <<= 1) se += __shfl_xor(se, off, 16);
        if (lj == 0) {
            float denom = mm + __logf(se);
            float numer = 0.f; int sm = 0;
#pragma unroll
            for (int i = 0; i < 16; ++i) { numer += cnum[i]; sm += cms[i]; }
            int last = label[b * Tn + sm - 1];
            partial[b] = denom - (numer + endT[last]);   // = -llh[b]
        }
    }

    // last block reduces partials -> out (proven election, wave 0 only)
    if (tid < 64) {
        int old = 0;
        if (tid == 0) {
            __threadfence();
            old = atomicAdd(cnt, 1);
        }
        old = __shfl(old, 0);
        if (old == Bn - 1) {
            __threadfence();             // acquire: other blocks' partial[] visible
            float pv = partial[tid];
#pragma unroll
            for (int off = 32; off > 0; off >>= 1) pv += __shfl_xor(pv, off);
            if (tid == 0) out[0] = pv * (1.0f / Bn);
        }
    }
}

extern "C" void kernel_launch(void* const* d_in, const int* in_sizes, int n_in,
                              void* d_out, int out_size, void* d_ws, size_t ws_size,
                              hipStream_t stream)
{
    // inputs: 0=length(unused) 1=word2vec 2=mask 3=label 4=W 5=b 6=start 7=end 8=trans
    const float* wv    = (const float*)d_in[1];
    const int*   mask  = (const int*)d_in[2];
    const int*   label = (const int*)d_in[3];
    const float* Wm    = (const float*)d_in[4];
    const float* bias  = (const float*)d_in[5];
    const float* st    = (const float*)d_in[6];
    const float* en    = (const float*)d_in[7];
    const float* tr    = (const float*)d_in[8];

    float* ws      = (float*)d_ws;
    float* Mq      = ws;                    // 1024*81 = 82944
    float* lgq     = ws + 82944;            // 1024*9  = 9216
    float* numq    = ws + 92160;            // 1024
    int*   msq     = (int*)(ws + 93184);    // 1024
    float* em0     = ws + 94208;            // 64*9 = 576
    float* partial = ws + 94784;            // 64
    int*   cnt     = (int*)(ws + 94848);    // 1
    float* out     = (float*)d_out;

    hipLaunchKernelGGL(emis_kernel, dim3(NBLK), dim3(256), 0, stream,
                       wv, Wm, bias, mask, label, tr, st,
                       Mq, lgq, numq, msq, em0, cnt);
    hipLaunchKernelGGL(comb_kernel, dim3(Bn), dim3(128), 0, stream,
                       Mq, lgq, numq, msq, em0, label, st, en,
                       partial, cnt, out);
}

// Round 7
// 47.482 us; speedup vs baseline: 1.4692x; 1.2934x over previous
//
#include <hip/hip_runtime.h>
#include <hip/hip_bf16.h>

// BERT_CRF, 16th-partitioned, MFMA emissions with K-SPLIT for occupancy.
// B=64, T=512, H=768, L=9.
//
// Six-round synthesis: every engine (MFMA direct, MFMA+DMA, VALU+LDS)
// converges to ~1.6 TB/s demand-read at <=8 waves/CU, while write-only
// fills hit 6.9 TB/s. The binding constraint is per-CU read concurrency
// (outstanding lines ~ waves), not the compute engine. MFMA's 16-row tile
// quantizes the grid to 2048 waves (8/CU); this round K-SPLITS each tile:
// wave = (tile, k-half), 12 MFMA steps over K=384, partner waves sum accs
// via a 2KB LDS buffer -> 4096 waves = 16/CU (2x all prior rounds).
//
// K1 emis_kernel: grid 1024 = (b, p of 16 x 32 rows), 256 thr (4 waves:
//   2 tiles x 2 k-halves).
//   A: stage W as bf16 MFMA B-frags (R2-proven layout), eTs, mask. barrier.
//   B: 12-step MFMA k-loop, R2-proven per-lane A loads (16 full 64B lines
//      per instr). kh=1 waves dump acc to accbuf; barrier; kh=0 waves add,
//      apply bias+exp -> ldsE. barrier.
//   C: w0/w1 = 16-step chunk products (R6-proven, eTs from LDS);
//      w2 = numerator partials; w3 = em0. barrier.
//   D: wave0 pair-combines 2 chunks -> Mq[bid], lgq[bid].
// K2 comb_kernel: verbatim R5/R6 (passed): 16->8->4 pair-combines + serial
//   fold of 4 + election reduce -> out. cnt zeroed by K1 block 0.

#define Bn 64
#define Tn 512
#define Hn 768
#define Ln 9
#define EMS 12     // padded LDS emission row stride (floats)
#define PT 32      // timesteps per block (2 chunks of 16)
#define NBLK 1024  // Bn * 16
#define KSTEPS 24  // 768 / 32 total
#define KH 12      // k-steps per half

typedef short bf16x8 __attribute__((ext_vector_type(8)));   // 8 bf16 (4 VGPRs)
typedef float f32x4  __attribute__((ext_vector_type(4)));   // 4 fp32 acc

__device__ __forceinline__ short f2bf(float f) {
    return (short)__builtin_bit_cast(unsigned short, __float2bfloat16(f));
}

// Proven pair-combine: (A,lgA) then (B,lgB) -> out (row-scaled) + outLg.
__device__ __forceinline__ void pair_combine(
    const float (*MA)[Ln], const float* lgA,
    const float (*MB)[Ln], const float* lgB,
    int r, float* outM, float* outLg)
{
    float mB = lgB[0];
#pragma unroll
    for (int k = 1; k < 9; ++k) mB = fmaxf(mB, lgB[k]);
    float tA[9];
#pragma unroll
    for (int k = 0; k < 9; ++k) tA[k] = MA[r][k] * __expf(lgB[k] - mB);
    float v[9];
#pragma unroll
    for (int jj = 0; jj < 9; ++jj) {
        float acc = tA[0] * MB[0][jj];
#pragma unroll
        for (int k = 1; k < 9; ++k) acc += tA[k] * MB[k][jj];
        v[jj] = acc;
    }
    float mx = v[0];
#pragma unroll
    for (int jj = 1; jj < 9; ++jj) mx = fmaxf(mx, v[jj]);
    float inv = 1.f / mx;
#pragma unroll
    for (int jj = 0; jj < 9; ++jj) outM[jj] = v[jj] * inv;
    *outLg = lgA[r] + mB + __logf(mx);
}

// ---------------- K1 ----------------
__global__ __launch_bounds__(256) void emis_kernel(
    const float* __restrict__ wv, const float* __restrict__ Wm,
    const float* __restrict__ bias, const int* __restrict__ mask,
    const int* __restrict__ label, const float* __restrict__ trans,
    const float* __restrict__ startT,
    float* __restrict__ Mq, float* __restrict__ lgq,
    float* __restrict__ numq, int* __restrict__ msq,
    float* __restrict__ em0, int* __restrict__ cnt)
{
    __shared__ bf16x8 wlds[KSTEPS * 64];       // 24576 B, W B-fragments
    __shared__ float4 accbuf[2][64];           // 2048 B, k-half partials
    __shared__ float  ldsE[PT][EMS];           // exp(emissions)
    __shared__ int    ldsM[PT];                // mask slice
    __shared__ float  eTs[81];                 // exp(transitions)
    __shared__ float  sM[2][Ln][Ln];           // 2 chunk matrices
    __shared__ float  sLg[2][Ln];

    const int tid   = threadIdx.x;
    const int lane  = tid & 63;
    const int wid   = tid >> 6;
    const int tile  = wid >> 1;                // 0,1: rows [tile*16, +16)
    const int kh    = wid & 1;                 // k half
    const int bid   = blockIdx.x;
    const int b     = bid >> 4;
    const int p     = bid & 15;
    const int tbase = p * PT;

    if (bid == 0 && tid == 0) cnt[0] = 0;      // K2 runs strictly after K1

    // ---- Phase A: stage W (R2-proven B-fragment layout), eTs, mask ----
    // entry (kk, lane): lane holds B[k = kk*32 + (lane>>4)*8 + j][n = lane&15],
    // B[k][n] = W[n][k]; n >= 9 -> zeros.
    for (int idx = tid; idx < KSTEPS * 64; idx += 256) {
        const int kk = idx >> 6, ln = idx & 63;
        const int n = ln & 15, kb2 = ln >> 4;
        bf16x8 v;
        if (n < Ln) {
            const float* src = Wm + n * Hn + kk * 32 + kb2 * 8;
#pragma unroll
            for (int j = 0; j < 8; ++j) v[j] = f2bf(src[j]);
        } else {
#pragma unroll
            for (int j = 0; j < 8; ++j) v[j] = 0;
        }
        wlds[idx] = v;
    }
    if (tid < 81) eTs[tid] = __expf(trans[tid]);
    if (tid < PT) ldsM[tid] = mask[b * Tn + tbase + tid];
    __syncthreads();

    // ---- Phase B: K-split MFMA emission ----
    {
        const int m  = lane & 15;              // A row within tile
        const int kb = lane >> 4;              // k-subblock (8 elems)
        const float* abase = wv + (size_t)(bid * PT + tile * 16 + m) * Hn
                           + kh * 384 + kb * 8;

        f32x4 acc = {0.f, 0.f, 0.f, 0.f};
#pragma unroll 4
        for (int kk = 0; kk < KH; ++kk) {
            float4 x0 = *reinterpret_cast<const float4*>(abase + kk * 32);
            float4 x1 = *reinterpret_cast<const float4*>(abase + kk * 32 + 4);
            bf16x8 a;
            a[0] = f2bf(x0.x); a[1] = f2bf(x0.y); a[2] = f2bf(x0.z); a[3] = f2bf(x0.w);
            a[4] = f2bf(x1.x); a[5] = f2bf(x1.y); a[6] = f2bf(x1.z); a[7] = f2bf(x1.w);
            bf16x8 bfr = wlds[(kh * KH + kk) * 64 + lane];
            acc = __builtin_amdgcn_mfma_f32_16x16x32_bf16(a, bfr, acc, 0, 0, 0);
        }

        if (kh == 1) {
            float4 o; o.x = acc[0]; o.y = acc[1]; o.z = acc[2]; o.w = acc[3];
            accbuf[tile][lane] = o;
        }
        __syncthreads();
        if (kh == 0) {
            // C/D layout: col = lane&15, row = (lane>>4)*4 + r (R2-proven).
            float4 o = accbuf[tile][lane];
            float ov[4] = {o.x, o.y, o.z, o.w};
            const int l = lane & 15;
            if (l < Ln) {
                const float bl = bias[l];
#pragma unroll
                for (int r = 0; r < 4; ++r) {
                    const int row = tile * 16 + (lane >> 4) * 4 + r;
                    ldsE[row][l] = __expf(acc[r] + ov[r] + bl);
                }
            }
        }
    }
    __syncthreads();

    // ---- Phase C: parallel tails by wave (R6-proven) ----
    if (wid < 2) {
        // chunk product for chunk wid (rows [wid*16, +16)), lanes 0..8,
        // eTs read from LDS at use (no 81-register array).
        if (lane < Ln) {
            const int r = lane;
            float v[9];
#pragma unroll
            for (int k = 0; k < 9; ++k) v[k] = (k == r) ? 1.f : 0.f;
            float lg = 0.f;
            const int sstart = (tbase + wid * 16 == 0) ? 1 : 0;   // skip t=0
            for (int s = sstart; s < 16; ++s) {
                const int lrow = wid * 16 + s;
                if (ldsM[lrow]) {
                    float4 e0v = *reinterpret_cast<const float4*>(&ldsE[lrow][0]);
                    float4 e1v = *reinterpret_cast<const float4*>(&ldsE[lrow][4]);
                    float  e8  = ldsE[lrow][8];
                    float e[9] = {e0v.x, e0v.y, e0v.z, e0v.w,
                                  e1v.x, e1v.y, e1v.z, e1v.w, e8};
                    float nv[9];
#pragma unroll
                    for (int jj = 0; jj < 9; ++jj) {
                        float a2 = v[0] * eTs[jj];
#pragma unroll
                        for (int k = 1; k < 9; ++k) a2 += v[k] * eTs[k * 9 + jj];
                        nv[jj] = a2 * e[jj];
                    }
                    float mx = nv[0];
#pragma unroll
                    for (int jj = 1; jj < 9; ++jj) mx = fmaxf(mx, nv[jj]);
                    float inv = 1.f / mx;
#pragma unroll
                    for (int jj = 0; jj < 9; ++jj) v[jj] = nv[jj] * inv;
                    lg += __logf(mx);
                }
            }
#pragma unroll
            for (int jj = 0; jj < 9; ++jj) sM[wid][r][jj] = v[jj];
            sLg[wid][r] = lg;
        }
    } else if (wid == 2) {
        // numerator partials for this block's 32 timesteps
        float part = 0.f; int ms = 0;
        if (lane < PT) {
            const int gt  = tbase + lane;
            const int tag = label[b * Tn + gt];
            const int mk  = ldsM[lane];
            ms = mk;
            if (gt == 0) {
                part = startT[tag] + __logf(ldsE[0][tag]);
            } else if (mk) {
                const int prev = label[b * Tn + gt - 1];
                part = trans[prev * Ln + tag] + __logf(ldsE[lane][tag]);
            }
        }
#pragma unroll
        for (int off = 32; off > 0; off >>= 1) {
            part += __shfl_xor(part, off);
            ms   += __shfl_xor(ms, off);
        }
        if (lane == 0) { numq[bid] = part; msq[bid] = ms; }
    } else {
        if (p == 0 && lane < Ln) em0[b * Ln + lane] = ldsE[0][lane];
    }
    __syncthreads();

    // ---- Phase D: wave0 combines the 2 chunks -> global ----
    if (wid == 0 && lane < Ln) {
        const int r = lane;
        float om[9], ol;
        pair_combine(sM[0], sLg[0], sM[1], sLg[1], r, om, &ol);
#pragma unroll
        for (int jj = 0; jj < 9; ++jj) Mq[bid * 81 + r * 9 + jj] = om[jj];
        lgq[bid * Ln + r] = ol;
    }
}

// ---------------- K2: combine 16 matrices per batch (R5/R6 verbatim) ----------------
__global__ __launch_bounds__(128) void comb_kernel(
    const float* __restrict__ Mq, const float* __restrict__ lgq,
    const float* __restrict__ numq, const int* __restrict__ msq,
    const float* __restrict__ em0, const int* __restrict__ label,
    const float* __restrict__ startT, const float* __restrict__ endT,
    float* __restrict__ partial, int* __restrict__ cnt, float* __restrict__ out)
{
    __shared__ float cO[16][Ln][Ln];
    __shared__ float cOl[16][Ln];
    __shared__ float cP[8][Ln][Ln];
    __shared__ float cPl[8][Ln];
    __shared__ float cQ[4][Ln][Ln];
    __shared__ float cQl[4][Ln];
    __shared__ float cem[Ln];
    __shared__ float cnum[16];
    __shared__ int   cms[16];

    const int b = blockIdx.x, tid = threadIdx.x;

    for (int i = tid; i < 16 * 81; i += 128) ((float*)cO)[i]  = Mq[b * 1296 + i];
    for (int i = tid; i < 16 * 9;  i += 128) ((float*)cOl)[i] = lgq[b * 144 + i];
    if (tid < Ln) cem[tid] = em0[b * Ln + tid];
    if (tid < 16) { cnum[tid] = numq[b * 16 + tid]; cms[tid] = msq[b * 16 + tid]; }
    __syncthreads();

    // 16 -> 8
    if (tid < 8 * Ln) {
        const int pp = tid / Ln, r = tid % Ln;
        float om[9], ol;
        pair_combine(cO[2 * pp], cOl[2 * pp], cO[2 * pp + 1], cOl[2 * pp + 1],
                     r, om, &ol);
#pragma unroll
        for (int jj = 0; jj < 9; ++jj) cP[pp][r][jj] = om[jj];
        cPl[pp][r] = ol;
    }
    __syncthreads();

    // 8 -> 4
    if (tid < 4 * Ln) {
        const int pp = tid / Ln, r = tid % Ln;
        float om[9], ol;
        pair_combine(cP[2 * pp], cPl[2 * pp], cP[2 * pp + 1], cPl[2 * pp + 1],
                     r, om, &ol);
#pragma unroll
        for (int jj = 0; jj < 9; ++jj) cQ[pp][r][jj] = om[jj];
        cQl[pp][r] = ol;
    }
    __syncthreads();

    // serial fold of 4 quarters + denominator (proven)
    if (tid < 16) {
        const int lj = tid;
        const float NEG = -1e30f;
        float la = (lj < Ln) ? (startT[lj] + __logf(cem[lj])) : NEG;
        for (int c = 0; c < 4; ++c) {
            float mc[9];
#pragma unroll
            for (int rr = 0; rr < 9; ++rr) mc[rr] = (lj < Ln) ? cQ[c][rr][lj] : 0.f;
            float x = (lj < Ln) ? (la + cQl[c][lj]) : NEG;
            float mm = x;
#pragma unroll
            for (int off = 1; off < 16; off <<= 1) mm = fmaxf(mm, __shfl_xor(mm, off, 16));
            float w = __expf(x - mm);                 // lj>=9 -> 0
            float sacc = 0.f;
#pragma unroll
            for (int rr = 0; rr < 9; ++rr) sacc += __shfl(w, rr, 16) * mc[rr];
            la = (lj < Ln) ? (mm + __logf(sacc)) : NEG;
        }
        float x = (lj < Ln) ? (la + endT[lj]) : NEG;
        float mm = x;
#pragma unroll
        for (int off = 1; off < 16; off <<= 1) mm = fmaxf(mm, __shfl_xor(mm, off, 16));
        float se = __expf(x - mm);
#pragma unroll
        for (int off = 1; off < 16; off <<= 1) se += __shfl_xor(se, off, 16);
        if (lj == 0) {
            float denom = mm + __logf(se);
            float numer = 0.f; int sm = 0;
#pragma unroll
            for (int i = 0; i < 16; ++i) { numer += cnum[i]; sm += cms[i]; }
            int last = label[b * Tn + sm - 1];
            partial[b] = denom - (numer + endT[last]);   // = -llh[b]
        }
    }

    // last block reduces partials -> out (proven election, wave 0 only)
    if (tid < 64) {
        int old = 0;
        if (tid == 0) {
            __threadfence();
            old = atomicAdd(cnt, 1);
        }
        old = __shfl(old, 0);
        if (old == Bn - 1) {
            __threadfence();             // acquire: other blocks' partial[] visible
            float pv = partial[tid];
#pragma unroll
            for (int off = 32; off > 0; off >>= 1) pv += __shfl_xor(pv, off);
            if (tid == 0) out[0] = pv * (1.0f / Bn);
        }
    }
}

extern "C" void kernel_launch(void* const* d_in, const int* in_sizes, int n_in,
                              void* d_out, int out_size, void* d_ws, size_t ws_size,
                              hipStream_t stream)
{
    // inputs: 0=length(unused) 1=word2vec 2=mask 3=label 4=W 5=b 6=start 7=end 8=trans
    const float* wv    = (const float*)d_in[1];
    const int*   mask  = (const int*)d_in[2];
    const int*   label = (const int*)d_in[3];
    const float* Wm    = (const float*)d_in[4];
    const float* bias  = (const float*)d_in[5];
    const float* st    = (const float*)d_in[6];
    const float* en    = (const float*)d_in[7];
    const float* tr    = (const float*)d_in[8];

    float* ws      = (float*)d_ws;
    float* Mq      = ws;                    // 1024*81 = 82944
    float* lgq     = ws + 82944;            // 1024*9  = 9216
    float* numq    = ws + 92160;            // 1024
    int*   msq     = (int*)(ws + 93184);    // 1024
    float* em0     = ws + 94208;            // 64*9 = 576
    float* partial = ws + 94784;            // 64
    int*   cnt     = (int*)(ws + 94848);    // 1
    float* out     = (float*)d_out;

    hipLaunchKernelGGL(emis_kernel, dim3(NBLK), dim3(256), 0, stream,
                       wv, Wm, bias, mask, label, tr, st,
                       Mq, lgq, numq, msq, em0, cnt);
    hipLaunchKernelGGL(comb_kernel, dim3(Bn), dim3(128), 0, stream,
                       Mq, lgq, numq, msq, em0, label, st, en,
                       partial, cnt, out);
}